// Round 5
// baseline (297.556 us; speedup 1.0000x reference)
//
#include <hip/hip_runtime.h>
#include <cstdint>
#include <cstddef>

// Dual attention (channel attention), B=16 S=512 D=1024 H=16 dk=64.
// Round 9. R8 budget: gemm3 73.5 + pack ~35 + gemm_o ~27 + mix ~12 +
// scores ~6 + softmax ~5 = 159us controllable of 290 total (rest: harness
// restore dispatches + launch gaps, ~22 dispatches/iter per Dispatch_Id
// arithmetic). R9 attacks the controllable part:
//   - pack's q/k/v f32->f16 round-trip (96MB read + 48MB write + re-read)
//     folded into gemm3: A is reg-staged from f32 (dwordx4 -> cvt ->
//     swizzled ds_write_b128), SAME LDS layout/fragment-reads/MFMA order/
//     epilogue as the proven body (bit-identical numerics). B keeps the
//     proven global_load_lds path from a weights-only pack (~4us).
//   - softmax launch removed: each mix block redundantly computes its
//     batch's 16x16 softmax from part (L2-hot); one block/batch writes attn.
// Pipeline:
//   1. pack_w: f32 -> fp16 weights (Wq,Wk,Wv,Wo)
//   2. gemm3 (z=3): Pq16,Pk16,Pv16 = f16(x@W^T+b), x read f32 directly
//   3. scores: part[(b,slice),i*16+j] = sum_{s in slice,c} Qf Kf  (MFMA)
//   4. mix: per-block softmax(part sum, x0.25) -> Mm = I + beta*attn;
//      xmix[r,64i+c] = f16( sum_j Mm[i,j]*Pv16[r,64j+c] ); attn -> d_out
//   5. out = f16 GEMM(xmix, Wo^T) + bo -> d_out
// mask (d_in[3]) and adj (d_in[4]) are unused by the reference.

#define DIM 1024

typedef _Float16 f16_t;
typedef _Float16 f16x4_t __attribute__((ext_vector_type(4)));
typedef _Float16 f16x8_t __attribute__((ext_vector_type(8)));
typedef float    f32x4_t __attribute__((ext_vector_type(4)));

__device__ __forceinline__ void async_ld16(const void* g, void* l) {
    __builtin_amdgcn_global_load_lds((const __attribute__((address_space(1))) void*)g,
                                     (__attribute__((address_space(3))) void*)l,
                                     16, 0, 0);
}

// ---------------------------------------------------------------- pack_w
// Weights only: 4 x 262144 float4 units = 1048576 units = 4096 blocks.
__global__ __launch_bounds__(256) void pack_w(
    const float* __restrict__ Wq, const float* __restrict__ Wk,
    const float* __restrict__ Wv, const float* __restrict__ Wo,
    f16_t* __restrict__ Bq, f16_t* __restrict__ Bk,
    f16_t* __restrict__ Bv, f16_t* __restrict__ Bo)
{
    const int u = blockIdx.x * 256 + threadIdx.x;
    const float* src; f16_t* dst; int i;
    if (u < 262144)       { src = Wq; dst = Bq; i = u; }
    else if (u < 524288)  { src = Wk; dst = Bk; i = u - 262144; }
    else if (u < 786432)  { src = Wv; dst = Bv; i = u - 524288; }
    else                  { src = Wo; dst = Bo; i = u - 786432; }
    float4 s = ((const float4*)src)[i];
    f16x4_t h;
    h[0] = (f16_t)s.x; h[1] = (f16_t)s.y; h[2] = (f16_t)s.z; h[3] = (f16_t)s.w;
    ((f16x4_t*)dst)[i] = h;
}

// --------------------------------------------------- GEMM body (f32 A in)
// C16[m,n] = f16( sum_k A[m,k]*B[n,k] + bias[n] ). A [8192,1024] f32
// row-major (raw input), B [1024,1024] f16 row-major (packed weights).
// Tile 128x128, BK=64, 4 waves. Identical LDS layout / fragment reads /
// MFMA order / epilogue as the proven R0 body; only A-staging differs:
// reg-staged f32 loads + in-register cvt + swizzled ds_write_b128 so the
// LDS image is bit-identical to what pack+global_load_lds produced:
//   As 16B-unit n (row=n>>3, u'=n&7) holds global f16 unit u'^(row&7).
__device__ __forceinline__ void gemm_body_f32A(
    const float* __restrict__ A, const f16_t* __restrict__ B,
    const float* __restrict__ bias, f16_t* __restrict__ C16,
    f16_t* As, f16_t* Bs, int tileM, int tileN)
{
    const int tid  = threadIdx.x;
    const int lane = tid & 63;
    const int w    = tid >> 6;
    const int wm = (w & 1) << 6;
    const int wn = (w >> 1) << 6;

    f32x4_t acc[4][4];
#pragma unroll
    for (int i = 0; i < 4; ++i)
#pragma unroll
        for (int j = 0; j < 4; ++j)
            acc[i][j] = (f32x4_t){0.f, 0.f, 0.f, 0.f};

    const int srow = lane >> 3;                       // B staging row in 8-chunk
    const int scol = ((lane & 7) ^ (lane >> 3)) << 3; // B swizzled fetch col
    const int arow = lane & 15;                       // mfma frag row/col
    const int sx   = lane & 7;                        // reader swizzle (= row&7)
    const int kqu  = lane >> 4;                       // frag k 16B-unit (0..3)

    // A reg-staging: thread writes LDS 16B-units n = tid + 256*s (s=0..3);
    // row = n>>3, u' = n&7, source global f16 unit u = u'^(row&7) ->
    // f32 elements u*8..u*8+7 (two dwordx4).
    int arows[4], acols[4];
#pragma unroll
    for (int s = 0; s < 4; ++s) {
        const int n = tid + (s << 8);
        arows[s] = n >> 3;
        acols[s] = ((n & 7) ^ ((n >> 3) & 7)) << 3;
    }

    for (int kt = 0; kt < 16; ++kt) {
        const int k0 = kt << 6;
        // B: proven async global->LDS path
#pragma unroll
        for (int t4 = 0; t4 < 4; ++t4) {
            const int row = (w << 5) + (t4 << 3);
            async_ld16(B + (size_t)(tileN + row + srow) * DIM + k0 + scol,
                       (void*)(Bs + row * 64));
        }
        // A: issue all 8 f32 dwordx4 loads, then cvt + ds_write_b128
        float4 ld[4][2];
#pragma unroll
        for (int s = 0; s < 4; ++s) {
            const float* src = A + (size_t)(tileM + arows[s]) * DIM + k0 + acols[s];
            ld[s][0] = ((const float4*)src)[0];
            ld[s][1] = ((const float4*)src)[1];
        }
#pragma unroll
        for (int s = 0; s < 4; ++s) {
            f16x8_t h;
            h[0] = (f16_t)ld[s][0].x; h[1] = (f16_t)ld[s][0].y;
            h[2] = (f16_t)ld[s][0].z; h[3] = (f16_t)ld[s][0].w;
            h[4] = (f16_t)ld[s][1].x; h[5] = (f16_t)ld[s][1].y;
            h[6] = (f16_t)ld[s][1].z; h[7] = (f16_t)ld[s][1].w;
            *(f16x8_t*)(As + (tid + (s << 8)) * 8) = h;
        }
        __syncthreads();
#pragma unroll
        for (int kk = 0; kk < 2; ++kk) {              // two 16B-unit groups
            const int cu = ((kk << 2) + kqu) ^ sx;    // swizzled LDS column unit
            f16x8_t af[4], bfv[4];
#pragma unroll
            for (int mt = 0; mt < 4; ++mt)
                af[mt] = *(const f16x8_t*)(As + (wm + (mt << 4) + arow) * 64 + (cu << 3));
#pragma unroll
            for (int nt = 0; nt < 4; ++nt)
                bfv[nt] = *(const f16x8_t*)(Bs + (wn + (nt << 4) + arow) * 64 + (cu << 3));
#pragma unroll
            for (int mt = 0; mt < 4; ++mt)
#pragma unroll
                for (int nt = 0; nt < 4; ++nt)
                    acc[mt][nt] = __builtin_amdgcn_mfma_f32_16x16x32_f16(
                        af[mt], bfv[nt], acc[mt][nt], 0, 0, 0);
        }
        __syncthreads();
    }

    // C/D layout: col = lane&15, row = (lane>>4)*4 + reg
    const int rq = (lane >> 4) << 2;
#pragma unroll
    for (int nt = 0; nt < 4; ++nt) {
        const int col = tileN + wn + (nt << 4) + arow;
        const float bv = bias[col];
#pragma unroll
        for (int mt = 0; mt < 4; ++mt) {
            const int row = tileM + wm + (mt << 4) + rq;
#pragma unroll
            for (int r = 0; r < 4; ++r)
                C16[(size_t)(row + r) * DIM + col] = (f16_t)(acc[mt][nt][r] + bv);
        }
    }
}

struct Gemm3Args {
    const float* A[3];    // q, k, v (raw f32)
    const f16_t* B[3];    // Bq, Bk, Bv (packed f16)
    const float* bias[3];
    f16_t*       C16[3];  // Pq16, Pk16, Pv16
};

// three projection GEMMs in one launch: grid (64, 8, 3) = 1536 blocks
__global__ __launch_bounds__(256) void gemm3(Gemm3Args args)
{
    __shared__ __align__(16) f16_t As[128 * 64];
    __shared__ __align__(16) f16_t Bs[128 * 64];
    const int z = blockIdx.z;
    gemm_body_f32A(args.A[z], args.B[z], args.bias[z], args.C16[z],
                   As, Bs, blockIdx.x * 128, blockIdx.y * 128);
}

// ---------------------------------------------------------------- gemm_o
// R0-proven all-f16 body (A via global_load_lds), f32 out.
__global__ __launch_bounds__(256) void gemm_o(
    const f16_t* __restrict__ A, const f16_t* __restrict__ B,
    const float* __restrict__ bias, float* __restrict__ C)
{
    __shared__ __align__(16) f16_t As[128 * 64];
    __shared__ __align__(16) f16_t Bs[128 * 64];
    const int tileM = blockIdx.x * 128, tileN = blockIdx.y * 128;
    const int tid  = threadIdx.x;
    const int lane = tid & 63;
    const int w    = tid >> 6;
    const int wm = (w & 1) << 6;
    const int wn = (w >> 1) << 6;

    f32x4_t acc[4][4];
#pragma unroll
    for (int i = 0; i < 4; ++i)
#pragma unroll
        for (int j = 0; j < 4; ++j)
            acc[i][j] = (f32x4_t){0.f, 0.f, 0.f, 0.f};

    const int srow = lane >> 3;
    const int scol = ((lane & 7) ^ (lane >> 3)) << 3;
    const int arow = lane & 15;
    const int sx   = lane & 7;
    const int kqu  = lane >> 4;

    for (int kt = 0; kt < 16; ++kt) {
        const int k0 = kt << 6;
#pragma unroll
        for (int t4 = 0; t4 < 4; ++t4) {
            const int row = (w << 5) + (t4 << 3);
            async_ld16(A + (size_t)(tileM + row + srow) * DIM + k0 + scol,
                       (void*)(As + row * 64));
            async_ld16(B + (size_t)(tileN + row + srow) * DIM + k0 + scol,
                       (void*)(Bs + row * 64));
        }
        __syncthreads();
#pragma unroll
        for (int kk = 0; kk < 2; ++kk) {
            const int cu = ((kk << 2) + kqu) ^ sx;
            f16x8_t af[4], bfv[4];
#pragma unroll
            for (int mt = 0; mt < 4; ++mt)
                af[mt] = *(const f16x8_t*)(As + (wm + (mt << 4) + arow) * 64 + (cu << 3));
#pragma unroll
            for (int nt = 0; nt < 4; ++nt)
                bfv[nt] = *(const f16x8_t*)(Bs + (wn + (nt << 4) + arow) * 64 + (cu << 3));
#pragma unroll
            for (int mt = 0; mt < 4; ++mt)
#pragma unroll
                for (int nt = 0; nt < 4; ++nt)
                    acc[mt][nt] = __builtin_amdgcn_mfma_f32_16x16x32_f16(
                        af[mt], bfv[nt], acc[mt][nt], 0, 0, 0);
        }
        __syncthreads();
    }

    const int rq = (lane >> 4) << 2;
#pragma unroll
    for (int nt = 0; nt < 4; ++nt) {
        const int col = tileN + wn + (nt << 4) + arow;
        const float bv = bias[col];
#pragma unroll
        for (int mt = 0; mt < 4; ++mt) {
            const int row = tileM + wm + (mt << 4) + rq;
#pragma unroll
            for (int r = 0; r < 4; ++r)
                C[(size_t)(row + r) * DIM + col] = acc[mt][nt][r] + bv;
        }
    }
}

// ---------------------------------------------------------------- scores
// part[(b*16+slice)*256 + i*16+j] = sum_{s in slice, c} Qf[b,i,s*64+c] *
// Kf[b,j,s*64+c]. Grid (16 b, 16 slices) = 256 blocks; wave w owns rows
// s = slice*32 + w*8 .. +7. No atomics, no fences (R7/R8 lesson).
__global__ __launch_bounds__(256) void scores_kernel(
    const f16_t* __restrict__ Pq16, const f16_t* __restrict__ Pk16,
    float* __restrict__ part)
{
    __shared__ float red[4][256];
    const int b = blockIdx.x;
    const int slice = blockIdx.y;
    const int lane = threadIdx.x & 63;
    const int w = threadIdx.x >> 6;
    const int m  = lane & 15;              // i (A rows) / j (B rows)
    const int q8 = (lane >> 4) << 3;       // k-offset within 32-chunk

    f32x4_t acc = (f32x4_t){0.f, 0.f, 0.f, 0.f};
    const int s0 = slice * 32 + w * 8;
#pragma unroll
    for (int ss = 0; ss < 8; ++ss) {
        const size_t rb = (size_t)(b * 512 + s0 + ss) * DIM;
        const f16_t* qrow = Pq16 + rb;
        const f16_t* krow = Pk16 + rb;
#pragma unroll
        for (int c0 = 0; c0 < 64; c0 += 32) {
            f16x8_t af = *(const f16x8_t*)(qrow + m * 64 + c0 + q8);
            f16x8_t bf = *(const f16x8_t*)(krow + m * 64 + c0 + q8);
            acc = __builtin_amdgcn_mfma_f32_16x16x32_f16(af, bf, acc, 0, 0, 0);
        }
    }
    // C/D: col(j) = lane&15, row(i) = (lane>>4)*4 + r
    const int rq = (lane >> 4) << 2;
#pragma unroll
    for (int r = 0; r < 4; ++r)
        red[w][(rq + r) * 16 + m] = acc[r];
    __syncthreads();
    const int t = threadIdx.x;
    part[(size_t)(b * 16 + slice) * 256 + t] =
        red[0][t] + red[1][t] + red[2][t] + red[3][t];
}

// ------------------------------------------------- channel mix (+softmax)
// Each block computes its batch's softmax from part redundantly (L2-hot,
// threads 0..15: thread i owns row i: 16 slices x 4 float4 loads), builds
// Mm = I + beta*attn in LDS, then mixes:
// xmix[r,64i+c] = f16( sum_j Mm[i,j] * Pv16[r,64j+c] ). 1024 blocks x 8 rows.
// One block per batch (blockIdx.x%64==0) writes attn to d_out.
__global__ __launch_bounds__(256) void mix_kernel(
    const f16_t* __restrict__ Pv16, const float* __restrict__ part,
    const float* __restrict__ beta_p,
    float* __restrict__ attn_out, f16_t* __restrict__ xmix)
{
    __shared__ float Msh[256];
    const int rbase = blockIdx.x * 8;
    const int b = rbase >> 9;
    const int t = threadIdx.x;
    if (t < 16) {
        const int i = t;
        float s[16];
#pragma unroll
        for (int j = 0; j < 16; ++j) s[j] = 0.f;
#pragma unroll 4
        for (int sl = 0; sl < 16; ++sl) {
            const float* pp = part + (size_t)(b * 16 + sl) * 256 + i * 16;
#pragma unroll
            for (int j4 = 0; j4 < 4; ++j4) {
                float4 v4 = ((const float4*)pp)[j4];
                s[j4 * 4 + 0] += v4.x; s[j4 * 4 + 1] += v4.y;
                s[j4 * 4 + 2] += v4.z; s[j4 * 4 + 3] += v4.w;
            }
        }
        float mx = -1e30f;
#pragma unroll
        for (int j = 0; j < 16; ++j) {
            s[j] *= 0.25f;                 // 1/sqrt(h), h=16
            mx = fmaxf(mx, s[j]);
        }
        float sum = 0.f;
#pragma unroll
        for (int j = 0; j < 16; ++j) { s[j] = expf(s[j] - mx); sum += s[j]; }
        const float inv = 1.f / sum;
        const float beta = beta_p[0];
        const bool wr_attn = (blockIdx.x & 63) == 0;
#pragma unroll
        for (int j = 0; j < 16; ++j) {
            float a = s[j] * inv;
            if (wr_attn) attn_out[(b * 16 + i) * 16 + j] = a;
            Msh[i * 16 + j] = beta * a + ((j == i) ? 1.f : 0.f);
        }
    }
    __syncthreads();
    const int w = threadIdx.x >> 6;
    const int lane = threadIdx.x & 63;
#pragma unroll
    for (int rr = 0; rr < 2; ++rr) {
        const int r = rbase + w * 2 + rr;
        const f16_t* vrow = Pv16 + (size_t)r * DIM;
        float v[16];
#pragma unroll
        for (int j = 0; j < 16; ++j) v[j] = (float)vrow[j * 64 + lane];
#pragma unroll
        for (int i = 0; i < 16; ++i) {
            float x = 0.f;
#pragma unroll
            for (int j = 0; j < 16; ++j) x += Msh[i * 16 + j] * v[j];
            xmix[(size_t)r * DIM + i * 64 + lane] = (f16_t)x;
        }
    }
}

// ---------------------------------------------------------------- launch
extern "C" void kernel_launch(void* const* d_in, const int* in_sizes, int n_in,
                              void* d_out, int out_size, void* d_ws, size_t ws_size,
                              hipStream_t stream)
{
    (void)in_sizes; (void)n_in; (void)out_size; (void)ws_size;
    const float* q    = (const float*)d_in[0];
    const float* k    = (const float*)d_in[1];
    const float* v    = (const float*)d_in[2];
    // d_in[3] mask, d_in[4] adj: unused by reference
    const float* Wq   = (const float*)d_in[5];
    const float* bq   = (const float*)d_in[6];
    const float* Wk   = (const float*)d_in[7];
    const float* bk   = (const float*)d_in[8];
    const float* Wv   = (const float*)d_in[9];
    const float* bv   = (const float*)d_in[10];
    const float* Wo   = (const float*)d_in[11];
    const float* bo   = (const float*)d_in[12];
    const float* beta = (const float*)d_in[13];

    float* out  = (float*)d_out;                     // [8192,1024]
    float* attn = (float*)d_out + 8388608;           // [16,16,16]

    char* p = (char*)d_ws;
    auto take = [&](size_t n) -> char* {
        char* cur = p; p += (n + 255) & ~(size_t)255; return cur;
    };
    f16_t* Bq = (f16_t*)take(2097152);
    f16_t* Bk = (f16_t*)take(2097152);
    f16_t* Bv = (f16_t*)take(2097152);
    f16_t* Bo = (f16_t*)take(2097152);
    f16_t* Pq16 = (f16_t*)take(16777216);
    f16_t* Pk16 = (f16_t*)take(16777216);
    f16_t* Pv16 = (f16_t*)take(16777216);
    f16_t* xmix = (f16_t*)take(16777216);
    float* part = (float*)take(262144);              // 16x16x256 partials

    pack_w<<<4096, 256, 0, stream>>>(Wq, Wk, Wv, Wo, Bq, Bk, Bv, Bo);

    Gemm3Args ga;
    ga.A[0] = q; ga.A[1] = k; ga.A[2] = v;
    ga.B[0] = Bq; ga.B[1] = Bk; ga.B[2] = Bv;
    ga.bias[0] = bq; ga.bias[1] = bk; ga.bias[2] = bv;
    ga.C16[0] = Pq16; ga.C16[1] = Pk16; ga.C16[2] = Pv16;
    gemm3<<<dim3(64, 8, 3), 256, 0, stream>>>(ga);

    scores_kernel<<<dim3(16, 16), 256, 0, stream>>>(Pq16, Pk16, part);
    mix_kernel<<<1024, 256, 0, stream>>>(Pv16, part, beta, attn, xmix);
    gemm_o<<<dim3(64, 8), 256, 0, stream>>>(xmix, Bo, bo, out);
}

// Round 6
// 288.103 us; speedup vs baseline: 1.0328x; 1.0328x over previous
//
#include <hip/hip_runtime.h>
#include <cstdint>
#include <cstddef>

// Dual attention (channel attention), B=16 S=512 D=1024 H=16 dk=64.
// Round 10: consolidation. R9's fused-A gemm3 regressed (73.5 -> 120us:
// serial load->wait->cvt->ds_write chain exposed full load latency each
// K-step; VALUBusy DOWN 38->28 = stalled waves, not extra work). Honoring
// the pre-stated fallback: revert to the R8 proven pack + global_load_lds
// gemm3. Keep R9's mix+softmax fusion (proven, saves a launch).
// Session evidence: every schedule restructure (R5 8-phase, R6 deep
// pipeline, R9 fused-A) regressed; every serialization-removal won.
// Pipeline:
//   1. pack: f32 -> fp16 (q,k,v,Wq,Wk,Wv,Wo)
//   2. gemm3 (z=3): Pq16,Pk16,Pv16 = f16(A@W^T+b)   [128^2 MFMA body]
//   3. scores: part[(b,slice),i*16+j] = sum_{s in slice,c} Qf Kf  (MFMA)
//   4. mix: per-block softmax(part sum, x0.25) -> Mm = I + beta*attn;
//      xmix[r,64i+c] = f16( sum_j Mm[i,j]*Pv16[r,64j+c] ); attn -> d_out
//   5. out = f16 GEMM(xmix, Wo^T) + bo -> d_out
// mask (d_in[3]) and adj (d_in[4]) are unused by the reference.

#define DIM 1024

typedef _Float16 f16_t;
typedef _Float16 f16x4_t __attribute__((ext_vector_type(4)));
typedef _Float16 f16x8_t __attribute__((ext_vector_type(8)));
typedef float    f32x4_t __attribute__((ext_vector_type(4)));

__device__ __forceinline__ void async_ld16(const void* g, void* l) {
    __builtin_amdgcn_global_load_lds((const __attribute__((address_space(1))) void*)g,
                                     (__attribute__((address_space(3))) void*)l,
                                     16, 0, 0);
}

// ---------------------------------------------------------------- pack kernel
// float4 units: q 2097152 | k 2097152 | v 2097152 | Wq 262144 | Wk 262144
//               | Wv 262144 | Wo 262144 => 7340032 units = 28672 blocks exactly.
__global__ __launch_bounds__(256) void pack_kernel(
    const float* __restrict__ q, const float* __restrict__ k, const float* __restrict__ v,
    const float* __restrict__ Wq, const float* __restrict__ Wk,
    const float* __restrict__ Wv, const float* __restrict__ Wo,
    f16_t* __restrict__ Aq, f16_t* __restrict__ Ak, f16_t* __restrict__ Av,
    f16_t* __restrict__ Bq, f16_t* __restrict__ Bk,
    f16_t* __restrict__ Bv, f16_t* __restrict__ Bo)
{
    const int u = blockIdx.x * 256 + threadIdx.x;
    const float* src; f16_t* dst; int i;
    if (u < 2097152)      { src = q;  dst = Aq; i = u; }
    else if (u < 4194304) { src = k;  dst = Ak; i = u - 2097152; }
    else if (u < 6291456) { src = v;  dst = Av; i = u - 4194304; }
    else if (u < 6553600) { src = Wq; dst = Bq; i = u - 6291456; }
    else if (u < 6815744) { src = Wk; dst = Bk; i = u - 6553600; }
    else if (u < 7077888) { src = Wv; dst = Bv; i = u - 6815744; }
    else                  { src = Wo; dst = Bo; i = u - 7077888; }
    float4 s = ((const float4*)src)[i];
    f16x4_t h;
    h[0] = (f16_t)s.x; h[1] = (f16_t)s.y; h[2] = (f16_t)s.z; h[3] = (f16_t)s.w;
    ((f16x4_t*)dst)[i] = h;
}

// ---------------------------------------------------------------- GEMM body
// R0-proven body. C[m,n] = sum_k A[m,k]*B[n,k] + bias[n]. A [8192,1024] f16
// row-major, B [1024,1024] f16 row-major (W [out,in] -> C = A@W^T). Tile
// 128x128, BK=64, 4 waves. LDS XOR-swizzled in 16B column units:
// LDS(row, cu) = global(row, cu ^ (row&7)) -> 0 bank conflicts (measured).
// Output: f16 to C16 if C16 != null, else f32 to C.
__device__ __forceinline__ void gemm_body(
    const f16_t* __restrict__ A, const f16_t* __restrict__ B,
    const float* __restrict__ bias, float* __restrict__ C, f16_t* __restrict__ C16,
    f16_t* As, f16_t* Bs, int tileM, int tileN)
{
    const int tid  = threadIdx.x;
    const int lane = tid & 63;
    const int w    = tid >> 6;
    const int wm = (w & 1) << 6;
    const int wn = (w >> 1) << 6;

    f32x4_t acc[4][4];
#pragma unroll
    for (int i = 0; i < 4; ++i)
#pragma unroll
        for (int j = 0; j < 4; ++j)
            acc[i][j] = (f32x4_t){0.f, 0.f, 0.f, 0.f};

    const int srow = lane >> 3;                       // staging row in 8-row chunk
    const int scol = ((lane & 7) ^ (lane >> 3)) << 3; // swizzled fetch col (elems)
    const int arow = lane & 15;                       // mfma frag row/col
    const int sx   = lane & 7;                        // reader swizzle (= row&7)
    const int kqu  = lane >> 4;                       // frag k 16B-unit (0..3)

    for (int kt = 0; kt < 16; ++kt) {
        const int k0 = kt << 6;
#pragma unroll
        for (int t = 0; t < 4; ++t) {
            const int row = (w << 5) + (t << 3);      // wave-uniform chunk base
            async_ld16(A + (size_t)(tileM + row + srow) * DIM + k0 + scol,
                       (void*)(As + row * 64));
            async_ld16(B + (size_t)(tileN + row + srow) * DIM + k0 + scol,
                       (void*)(Bs + row * 64));
        }
        __syncthreads();
#pragma unroll
        for (int kk = 0; kk < 2; ++kk) {              // two 16B-unit groups
            const int cu = ((kk << 2) + kqu) ^ sx;    // swizzled LDS column unit
            f16x8_t af[4], bfv[4];
#pragma unroll
            for (int mt = 0; mt < 4; ++mt)
                af[mt] = *(const f16x8_t*)(As + (wm + (mt << 4) + arow) * 64 + (cu << 3));
#pragma unroll
            for (int nt = 0; nt < 4; ++nt)
                bfv[nt] = *(const f16x8_t*)(Bs + (wn + (nt << 4) + arow) * 64 + (cu << 3));
#pragma unroll
            for (int mt = 0; mt < 4; ++mt)
#pragma unroll
                for (int nt = 0; nt < 4; ++nt)
                    acc[mt][nt] = __builtin_amdgcn_mfma_f32_16x16x32_f16(
                        af[mt], bfv[nt], acc[mt][nt], 0, 0, 0);
        }
        __syncthreads();
    }

    // C/D layout: col = lane&15, row = (lane>>4)*4 + reg
    const int rq = (lane >> 4) << 2;
    if (C16) {
#pragma unroll
        for (int nt = 0; nt < 4; ++nt) {
            const int col = tileN + wn + (nt << 4) + arow;
            const float bv = bias[col];
#pragma unroll
            for (int mt = 0; mt < 4; ++mt) {
                const int row = tileM + wm + (mt << 4) + rq;
#pragma unroll
                for (int r = 0; r < 4; ++r)
                    C16[(size_t)(row + r) * DIM + col] = (f16_t)(acc[mt][nt][r] + bv);
            }
        }
    } else {
#pragma unroll
        for (int nt = 0; nt < 4; ++nt) {
            const int col = tileN + wn + (nt << 4) + arow;
            const float bv = bias[col];
#pragma unroll
            for (int mt = 0; mt < 4; ++mt) {
                const int row = tileM + wm + (mt << 4) + rq;
#pragma unroll
                for (int r = 0; r < 4; ++r)
                    C[(size_t)(row + r) * DIM + col] = acc[mt][nt][r] + bv;
            }
        }
    }
}

struct Gemm3Args {
    const f16_t* A[3];
    const f16_t* B[3];
    const float* bias[3];
    f16_t*       C16[3];  // Pq16, Pk16, Pv16 (all f16 out)
};

// three projection GEMMs in one launch: grid (64, 8, 3) = 1536 blocks
__global__ __launch_bounds__(256) void gemm3(Gemm3Args args)
{
    __shared__ __align__(16) f16_t As[128 * 64];
    __shared__ __align__(16) f16_t Bs[128 * 64];
    const int z = blockIdx.z;
    gemm_body(args.A[z], args.B[z], args.bias[z], nullptr, args.C16[z],
              As, Bs, blockIdx.x * 128, blockIdx.y * 128);
}

// output projection, f32 out
__global__ __launch_bounds__(256) void gemm_o(
    const f16_t* __restrict__ A, const f16_t* __restrict__ B,
    const float* __restrict__ bias, float* __restrict__ C)
{
    __shared__ __align__(16) f16_t As[128 * 64];
    __shared__ __align__(16) f16_t Bs[128 * 64];
    gemm_body(A, B, bias, C, nullptr, As, Bs, blockIdx.x * 128, blockIdx.y * 128);
}

// ---------------------------------------------------------------- scores
// part[(b*16+slice)*256 + i*16+j] = sum_{s in slice, c} Qf[b,i,s*64+c] *
// Kf[b,j,s*64+c]. Grid (16 b, 16 slices) = 256 blocks; wave w owns rows
// s = slice*32 + w*8 .. +7. No atomics, no fences (R7/R8 lesson).
__global__ __launch_bounds__(256) void scores_kernel(
    const f16_t* __restrict__ Pq16, const f16_t* __restrict__ Pk16,
    float* __restrict__ part)
{
    __shared__ float red[4][256];
    const int b = blockIdx.x;
    const int slice = blockIdx.y;
    const int lane = threadIdx.x & 63;
    const int w = threadIdx.x >> 6;
    const int m  = lane & 15;              // i (A rows) / j (B rows)
    const int q8 = (lane >> 4) << 3;       // k-offset within 32-chunk

    f32x4_t acc = (f32x4_t){0.f, 0.f, 0.f, 0.f};
    const int s0 = slice * 32 + w * 8;
#pragma unroll
    for (int ss = 0; ss < 8; ++ss) {
        const size_t rb = (size_t)(b * 512 + s0 + ss) * DIM;
        const f16_t* qrow = Pq16 + rb;
        const f16_t* krow = Pk16 + rb;
#pragma unroll
        for (int c0 = 0; c0 < 64; c0 += 32) {
            f16x8_t af = *(const f16x8_t*)(qrow + m * 64 + c0 + q8);
            f16x8_t bf = *(const f16x8_t*)(krow + m * 64 + c0 + q8);
            acc = __builtin_amdgcn_mfma_f32_16x16x32_f16(af, bf, acc, 0, 0, 0);
        }
    }
    // C/D: col(j) = lane&15, row(i) = (lane>>4)*4 + r
    const int rq = (lane >> 4) << 2;
#pragma unroll
    for (int r = 0; r < 4; ++r)
        red[w][(rq + r) * 16 + m] = acc[r];
    __syncthreads();
    const int t = threadIdx.x;
    part[(size_t)(b * 16 + slice) * 256 + t] =
        red[0][t] + red[1][t] + red[2][t] + red[3][t];
}

// ------------------------------------------------- channel mix (+softmax)
// Each block computes its batch's softmax from part redundantly (L2-hot,
// threads 0..15: thread i owns row i), builds Mm = I + beta*attn in LDS,
// then mixes: xmix[r,64i+c] = f16( sum_j Mm[i,j] * Pv16[r,64j+c] ).
// 1024 blocks x 8 rows. One block per batch (blockIdx.x%64==0) writes attn.
__global__ __launch_bounds__(256) void mix_kernel(
    const f16_t* __restrict__ Pv16, const float* __restrict__ part,
    const float* __restrict__ beta_p,
    float* __restrict__ attn_out, f16_t* __restrict__ xmix)
{
    __shared__ float Msh[256];
    const int rbase = blockIdx.x * 8;
    const int b = rbase >> 9;
    const int t = threadIdx.x;
    if (t < 16) {
        const int i = t;
        float s[16];
#pragma unroll
        for (int j = 0; j < 16; ++j) s[j] = 0.f;
#pragma unroll 4
        for (int sl = 0; sl < 16; ++sl) {
            const float* pp = part + (size_t)(b * 16 + sl) * 256 + i * 16;
#pragma unroll
            for (int j4 = 0; j4 < 4; ++j4) {
                float4 v4 = ((const float4*)pp)[j4];
                s[j4 * 4 + 0] += v4.x; s[j4 * 4 + 1] += v4.y;
                s[j4 * 4 + 2] += v4.z; s[j4 * 4 + 3] += v4.w;
            }
        }
        float mx = -1e30f;
#pragma unroll
        for (int j = 0; j < 16; ++j) {
            s[j] *= 0.25f;                 // 1/sqrt(h), h=16
            mx = fmaxf(mx, s[j]);
        }
        float sum = 0.f;
#pragma unroll
        for (int j = 0; j < 16; ++j) { s[j] = expf(s[j] - mx); sum += s[j]; }
        const float inv = 1.f / sum;
        const float beta = beta_p[0];
        const bool wr_attn = (blockIdx.x & 63) == 0;
#pragma unroll
        for (int j = 0; j < 16; ++j) {
            float a = s[j] * inv;
            if (wr_attn) attn_out[(b * 16 + i) * 16 + j] = a;
            Msh[i * 16 + j] = beta * a + ((j == i) ? 1.f : 0.f);
        }
    }
    __syncthreads();
    const int w = threadIdx.x >> 6;
    const int lane = threadIdx.x & 63;
#pragma unroll
    for (int rr = 0; rr < 2; ++rr) {
        const int r = rbase + w * 2 + rr;
        const f16_t* vrow = Pv16 + (size_t)r * DIM;
        float v[16];
#pragma unroll
        for (int j = 0; j < 16; ++j) v[j] = (float)vrow[j * 64 + lane];
#pragma unroll
        for (int i = 0; i < 16; ++i) {
            float x = 0.f;
#pragma unroll
            for (int j = 0; j < 16; ++j) x += Msh[i * 16 + j] * v[j];
            xmix[(size_t)r * DIM + i * 64 + lane] = (f16_t)x;
        }
    }
}

// ---------------------------------------------------------------- launch
extern "C" void kernel_launch(void* const* d_in, const int* in_sizes, int n_in,
                              void* d_out, int out_size, void* d_ws, size_t ws_size,
                              hipStream_t stream)
{
    (void)in_sizes; (void)n_in; (void)out_size; (void)ws_size;
    const float* q    = (const float*)d_in[0];
    const float* k    = (const float*)d_in[1];
    const float* v    = (const float*)d_in[2];
    // d_in[3] mask, d_in[4] adj: unused by reference
    const float* Wq   = (const float*)d_in[5];
    const float* bq   = (const float*)d_in[6];
    const float* Wk   = (const float*)d_in[7];
    const float* bk   = (const float*)d_in[8];
    const float* Wv   = (const float*)d_in[9];
    const float* bv   = (const float*)d_in[10];
    const float* Wo   = (const float*)d_in[11];
    const float* bo   = (const float*)d_in[12];
    const float* beta = (const float*)d_in[13];

    float* out  = (float*)d_out;                     // [8192,1024]
    float* attn = (float*)d_out + 8388608;           // [16,16,16]

    char* p = (char*)d_ws;
    auto take = [&](size_t n) -> char* {
        char* cur = p; p += (n + 255) & ~(size_t)255; return cur;
    };
    f16_t* Aq = (f16_t*)take(16777216);
    f16_t* Ak = (f16_t*)take(16777216);
    f16_t* Av = (f16_t*)take(16777216);
    f16_t* Bq = (f16_t*)take(2097152);
    f16_t* Bk = (f16_t*)take(2097152);
    f16_t* Bv = (f16_t*)take(2097152);
    f16_t* Bo = (f16_t*)take(2097152);
    f16_t* Pq16 = (f16_t*)take(16777216);
    f16_t* Pk16 = (f16_t*)take(16777216);
    f16_t* Pv16 = (f16_t*)take(16777216);
    float* part = (float*)take(262144);              // 16x16x256 partials
    f16_t* xmix = Aq;  // Aq dead after gemm3; reuse for xmix

    pack_kernel<<<28672, 256, 0, stream>>>(q, k, v, Wq, Wk, Wv, Wo,
                                           Aq, Ak, Av, Bq, Bk, Bv, Bo);

    Gemm3Args ga;
    ga.A[0] = Aq; ga.A[1] = Ak; ga.A[2] = Av;
    ga.B[0] = Bq; ga.B[1] = Bk; ga.B[2] = Bv;
    ga.bias[0] = bq; ga.bias[1] = bk; ga.bias[2] = bv;
    ga.C16[0] = Pq16; ga.C16[1] = Pk16; ga.C16[2] = Pv16;
    gemm3<<<dim3(64, 8, 3), 256, 0, stream>>>(ga);

    scores_kernel<<<dim3(16, 16), 256, 0, stream>>>(Pq16, Pk16, part);
    mix_kernel<<<1024, 256, 0, stream>>>(Pv16, part, beta, attn, xmix);
    gemm_o<<<dim3(64, 8), 256, 0, stream>>>(xmix, Bo, bo, out);
}

// Round 7
// 285.017 us; speedup vs baseline: 1.0440x; 1.0108x over previous
//
#include <hip/hip_runtime.h>
#include <cstdint>
#include <cstddef>

// Dual attention (channel attention), B=16 S=512 D=1024 H=16 dk=64.
// Round 11: polish of the R10 best (288.1us). Two G13-class fixes:
//   - mix_kernel: V loads were 2B/lane scalar f16 (the classic missed
//     vectorization); now f16x8 16B/lane, thread=(rloc,i8,u) computes
//     8i x 8c via mixed fma. Grid 512x256 (16 rows/block).
//   - pack: 32B read / 16B write per thread (2xfloat4 -> f16x8), grid
//     halved to 14336.
// Everything else identical to the R10 consolidation (proven bodies).
// Session evidence: schedule restructures 0/3 (R5 8-phase, R6 deep
// pipeline, R9 fused-A all regressed); serialization-removal + proven-body
// consolidation + vectorization wins.
// Pipeline:
//   1. pack: f32 -> fp16 (q,k,v,Wq,Wk,Wv,Wo)
//   2. gemm3 (z=3): Pq16,Pk16,Pv16 = f16(A@W^T+b)   [128^2 MFMA body]
//   3. scores: part[(b,slice),i*16+j] = sum_{s in slice,c} Qf Kf  (MFMA)
//   4. mix: per-block softmax(part sum, x0.25) -> Mm = I + beta*attn;
//      xmix[r,64i+c] = f16( sum_j Mm[i,j]*Pv16[r,64j+c] ); attn -> d_out
//   5. out = f16 GEMM(xmix, Wo^T) + bo -> d_out
// mask (d_in[3]) and adj (d_in[4]) are unused by the reference.

#define DIM 1024

typedef _Float16 f16_t;
typedef _Float16 f16x4_t __attribute__((ext_vector_type(4)));
typedef _Float16 f16x8_t __attribute__((ext_vector_type(8)));
typedef float    f32x4_t __attribute__((ext_vector_type(4)));

__device__ __forceinline__ void async_ld16(const void* g, void* l) {
    __builtin_amdgcn_global_load_lds((const __attribute__((address_space(1))) void*)g,
                                     (__attribute__((address_space(3))) void*)l,
                                     16, 0, 0);
}

// ---------------------------------------------------------------- pack kernel
// 32B/thread: float4-PAIR units. q 1048576 | k 1048576 | v 1048576
// | Wq 131072 | Wk 131072 | Wv 131072 | Wo 131072 => 3670016 pairs
// = 14336 blocks exactly.
__global__ __launch_bounds__(256) void pack_kernel(
    const float* __restrict__ q, const float* __restrict__ k, const float* __restrict__ v,
    const float* __restrict__ Wq, const float* __restrict__ Wk,
    const float* __restrict__ Wv, const float* __restrict__ Wo,
    f16_t* __restrict__ Aq, f16_t* __restrict__ Ak, f16_t* __restrict__ Av,
    f16_t* __restrict__ Bq, f16_t* __restrict__ Bk,
    f16_t* __restrict__ Bv, f16_t* __restrict__ Bo)
{
    const int u = blockIdx.x * 256 + threadIdx.x;
    const float* src; f16_t* dst; int i;
    if (u < 1048576)      { src = q;  dst = Aq; i = u; }
    else if (u < 2097152) { src = k;  dst = Ak; i = u - 1048576; }
    else if (u < 3145728) { src = v;  dst = Av; i = u - 2097152; }
    else if (u < 3276800) { src = Wq; dst = Bq; i = u - 3145728; }
    else if (u < 3407872) { src = Wk; dst = Bk; i = u - 3276800; }
    else if (u < 3538944) { src = Wv; dst = Bv; i = u - 3407872; }
    else                  { src = Wo; dst = Bo; i = u - 3538944; }
    float4 s0 = ((const float4*)src)[2 * i];
    float4 s1 = ((const float4*)src)[2 * i + 1];
    f16x8_t h;
    h[0] = (f16_t)s0.x; h[1] = (f16_t)s0.y; h[2] = (f16_t)s0.z; h[3] = (f16_t)s0.w;
    h[4] = (f16_t)s1.x; h[5] = (f16_t)s1.y; h[6] = (f16_t)s1.z; h[7] = (f16_t)s1.w;
    ((f16x8_t*)dst)[i] = h;
}

// ---------------------------------------------------------------- GEMM body
// R0-proven body. C[m,n] = sum_k A[m,k]*B[n,k] + bias[n]. A [8192,1024] f16
// row-major, B [1024,1024] f16 row-major (W [out,in] -> C = A@W^T). Tile
// 128x128, BK=64, 4 waves. LDS XOR-swizzled in 16B column units:
// LDS(row, cu) = global(row, cu ^ (row&7)) -> 0 bank conflicts (measured).
// Output: f16 to C16 if C16 != null, else f32 to C.
__device__ __forceinline__ void gemm_body(
    const f16_t* __restrict__ A, const f16_t* __restrict__ B,
    const float* __restrict__ bias, float* __restrict__ C, f16_t* __restrict__ C16,
    f16_t* As, f16_t* Bs, int tileM, int tileN)
{
    const int tid  = threadIdx.x;
    const int lane = tid & 63;
    const int w    = tid >> 6;
    const int wm = (w & 1) << 6;
    const int wn = (w >> 1) << 6;

    f32x4_t acc[4][4];
#pragma unroll
    for (int i = 0; i < 4; ++i)
#pragma unroll
        for (int j = 0; j < 4; ++j)
            acc[i][j] = (f32x4_t){0.f, 0.f, 0.f, 0.f};

    const int srow = lane >> 3;                       // staging row in 8-row chunk
    const int scol = ((lane & 7) ^ (lane >> 3)) << 3; // swizzled fetch col (elems)
    const int arow = lane & 15;                       // mfma frag row/col
    const int sx   = lane & 7;                        // reader swizzle (= row&7)
    const int kqu  = lane >> 4;                       // frag k 16B-unit (0..3)

    for (int kt = 0; kt < 16; ++kt) {
        const int k0 = kt << 6;
#pragma unroll
        for (int t = 0; t < 4; ++t) {
            const int row = (w << 5) + (t << 3);      // wave-uniform chunk base
            async_ld16(A + (size_t)(tileM + row + srow) * DIM + k0 + scol,
                       (void*)(As + row * 64));
            async_ld16(B + (size_t)(tileN + row + srow) * DIM + k0 + scol,
                       (void*)(Bs + row * 64));
        }
        __syncthreads();
#pragma unroll
        for (int kk = 0; kk < 2; ++kk) {              // two 16B-unit groups
            const int cu = ((kk << 2) + kqu) ^ sx;    // swizzled LDS column unit
            f16x8_t af[4], bfv[4];
#pragma unroll
            for (int mt = 0; mt < 4; ++mt)
                af[mt] = *(const f16x8_t*)(As + (wm + (mt << 4) + arow) * 64 + (cu << 3));
#pragma unroll
            for (int nt = 0; nt < 4; ++nt)
                bfv[nt] = *(const f16x8_t*)(Bs + (wn + (nt << 4) + arow) * 64 + (cu << 3));
#pragma unroll
            for (int mt = 0; mt < 4; ++mt)
#pragma unroll
                for (int nt = 0; nt < 4; ++nt)
                    acc[mt][nt] = __builtin_amdgcn_mfma_f32_16x16x32_f16(
                        af[mt], bfv[nt], acc[mt][nt], 0, 0, 0);
        }
        __syncthreads();
    }

    // C/D layout: col = lane&15, row = (lane>>4)*4 + reg
    const int rq = (lane >> 4) << 2;
    if (C16) {
#pragma unroll
        for (int nt = 0; nt < 4; ++nt) {
            const int col = tileN + wn + (nt << 4) + arow;
            const float bv = bias[col];
#pragma unroll
            for (int mt = 0; mt < 4; ++mt) {
                const int row = tileM + wm + (mt << 4) + rq;
#pragma unroll
                for (int r = 0; r < 4; ++r)
                    C16[(size_t)(row + r) * DIM + col] = (f16_t)(acc[mt][nt][r] + bv);
            }
        }
    } else {
#pragma unroll
        for (int nt = 0; nt < 4; ++nt) {
            const int col = tileN + wn + (nt << 4) + arow;
            const float bv = bias[col];
#pragma unroll
            for (int mt = 0; mt < 4; ++mt) {
                const int row = tileM + wm + (mt << 4) + rq;
#pragma unroll
                for (int r = 0; r < 4; ++r)
                    C[(size_t)(row + r) * DIM + col] = acc[mt][nt][r] + bv;
            }
        }
    }
}

struct Gemm3Args {
    const f16_t* A[3];
    const f16_t* B[3];
    const float* bias[3];
    f16_t*       C16[3];  // Pq16, Pk16, Pv16 (all f16 out)
};

// three projection GEMMs in one launch: grid (64, 8, 3) = 1536 blocks
__global__ __launch_bounds__(256) void gemm3(Gemm3Args args)
{
    __shared__ __align__(16) f16_t As[128 * 64];
    __shared__ __align__(16) f16_t Bs[128 * 64];
    const int z = blockIdx.z;
    gemm_body(args.A[z], args.B[z], args.bias[z], nullptr, args.C16[z],
              As, Bs, blockIdx.x * 128, blockIdx.y * 128);
}

// output projection, f32 out
__global__ __launch_bounds__(256) void gemm_o(
    const f16_t* __restrict__ A, const f16_t* __restrict__ B,
    const float* __restrict__ bias, float* __restrict__ C)
{
    __shared__ __align__(16) f16_t As[128 * 64];
    __shared__ __align__(16) f16_t Bs[128 * 64];
    gemm_body(A, B, bias, C, nullptr, As, Bs, blockIdx.x * 128, blockIdx.y * 128);
}

// ---------------------------------------------------------------- scores
// part[(b*16+slice)*256 + i*16+j] = sum_{s in slice, c} Qf[b,i,s*64+c] *
// Kf[b,j,s*64+c]. Grid (16 b, 16 slices) = 256 blocks; wave w owns rows
// s = slice*32 + w*8 .. +7. No atomics, no fences (R7/R8 lesson).
__global__ __launch_bounds__(256) void scores_kernel(
    const f16_t* __restrict__ Pq16, const f16_t* __restrict__ Pk16,
    float* __restrict__ part)
{
    __shared__ float red[4][256];
    const int b = blockIdx.x;
    const int slice = blockIdx.y;
    const int lane = threadIdx.x & 63;
    const int w = threadIdx.x >> 6;
    const int m  = lane & 15;              // i (A rows) / j (B rows)
    const int q8 = (lane >> 4) << 3;       // k-offset within 32-chunk

    f32x4_t acc = (f32x4_t){0.f, 0.f, 0.f, 0.f};
    const int s0 = slice * 32 + w * 8;
#pragma unroll
    for (int ss = 0; ss < 8; ++ss) {
        const size_t rb = (size_t)(b * 512 + s0 + ss) * DIM;
        const f16_t* qrow = Pq16 + rb;
        const f16_t* krow = Pk16 + rb;
#pragma unroll
        for (int c0 = 0; c0 < 64; c0 += 32) {
            f16x8_t af = *(const f16x8_t*)(qrow + m * 64 + c0 + q8);
            f16x8_t bf = *(const f16x8_t*)(krow + m * 64 + c0 + q8);
            acc = __builtin_amdgcn_mfma_f32_16x16x32_f16(af, bf, acc, 0, 0, 0);
        }
    }
    // C/D: col(j) = lane&15, row(i) = (lane>>4)*4 + r
    const int rq = (lane >> 4) << 2;
#pragma unroll
    for (int r = 0; r < 4; ++r)
        red[w][(rq + r) * 16 + m] = acc[r];
    __syncthreads();
    const int t = threadIdx.x;
    part[(size_t)(b * 16 + slice) * 256 + t] =
        red[0][t] + red[1][t] + red[2][t] + red[3][t];
}

// ------------------------------------------------- channel mix (+softmax)
// Each block computes its batch's softmax from part redundantly (L2-hot,
// threads 0..15: thread i owns row i), builds Mm = I + beta*attn in LDS,
// then mixes with VECTORIZED 16B/lane V loads (R10's were 2B/lane scalar):
// thread t = (rloc = t>>4, i8 = (t>>3)&1, u = t&7); r = blk*16 + rloc;
// loads v[j] = Pv16[r, j*64 + u*8 .. +7] (f16x8), computes i in
// i8*8..i8*8+7: xmix[r, i*64+u*8+c] = f16( sum_j Msh[i*16+j]*v[j][c] ).
// Grid 512 blocks x 16 rows. One block per batch (blockIdx.x%32==0)
// writes attn to d_out.
__global__ __launch_bounds__(256) void mix_kernel(
    const f16_t* __restrict__ Pv16, const float* __restrict__ part,
    const float* __restrict__ beta_p,
    float* __restrict__ attn_out, f16_t* __restrict__ xmix)
{
    __shared__ float Msh[256];
    const int rbase = blockIdx.x * 16;
    const int b = blockIdx.x >> 5;         // 32 blocks per batch
    const int t = threadIdx.x;
    if (t < 16) {
        const int i = t;
        float s[16];
#pragma unroll
        for (int j = 0; j < 16; ++j) s[j] = 0.f;
#pragma unroll 4
        for (int sl = 0; sl < 16; ++sl) {
            const float* pp = part + (size_t)(b * 16 + sl) * 256 + i * 16;
#pragma unroll
            for (int j4 = 0; j4 < 4; ++j4) {
                float4 v4 = ((const float4*)pp)[j4];
                s[j4 * 4 + 0] += v4.x; s[j4 * 4 + 1] += v4.y;
                s[j4 * 4 + 2] += v4.z; s[j4 * 4 + 3] += v4.w;
            }
        }
        float mx = -1e30f;
#pragma unroll
        for (int j = 0; j < 16; ++j) {
            s[j] *= 0.25f;                 // 1/sqrt(h), h=16
            mx = fmaxf(mx, s[j]);
        }
        float sum = 0.f;
#pragma unroll
        for (int j = 0; j < 16; ++j) { s[j] = expf(s[j] - mx); sum += s[j]; }
        const float inv = 1.f / sum;
        const float beta = beta_p[0];
        const bool wr_attn = (blockIdx.x & 31) == 0;
#pragma unroll
        for (int j = 0; j < 16; ++j) {
            float a = s[j] * inv;
            if (wr_attn) attn_out[(b * 16 + i) * 16 + j] = a;
            Msh[i * 16 + j] = beta * a + ((j == i) ? 1.f : 0.f);
        }
    }
    __syncthreads();
    const int u    = t & 7;                // 8-channel unit within head
    const int i8   = (t >> 3) & 1;         // i half (0: i=0..7, 1: i=8..15)
    const int rloc = t >> 4;               // row within block (0..15)
    const int r = rbase + rloc;
    const f16_t* vrow = Pv16 + (size_t)r * DIM + u * 8;
    f16x8_t v[16];
#pragma unroll
    for (int j = 0; j < 16; ++j)
        v[j] = *(const f16x8_t*)(vrow + j * 64);
    f16_t* orow = xmix + (size_t)r * DIM + u * 8;
#pragma unroll
    for (int ii = 0; ii < 8; ++ii) {
        const int i = i8 * 8 + ii;
        const float* mrow = Msh + i * 16;
        float acc[8];
#pragma unroll
        for (int c = 0; c < 8; ++c) acc[c] = 0.f;
#pragma unroll
        for (int j = 0; j < 16; ++j) {
            const float m = mrow[j];
#pragma unroll
            for (int c = 0; c < 8; ++c)
                acc[c] += m * (float)v[j][c];   // v_fma_mix
        }
        f16x8_t o;
#pragma unroll
        for (int c = 0; c < 8; ++c) o[c] = (f16_t)acc[c];
        *(f16x8_t*)(orow + i * 64) = o;
    }
}

// ---------------------------------------------------------------- launch
extern "C" void kernel_launch(void* const* d_in, const int* in_sizes, int n_in,
                              void* d_out, int out_size, void* d_ws, size_t ws_size,
                              hipStream_t stream)
{
    (void)in_sizes; (void)n_in; (void)out_size; (void)ws_size;
    const float* q    = (const float*)d_in[0];
    const float* k    = (const float*)d_in[1];
    const float* v    = (const float*)d_in[2];
    // d_in[3] mask, d_in[4] adj: unused by reference
    const float* Wq   = (const float*)d_in[5];
    const float* bq   = (const float*)d_in[6];
    const float* Wk   = (const float*)d_in[7];
    const float* bk   = (const float*)d_in[8];
    const float* Wv   = (const float*)d_in[9];
    const float* bv   = (const float*)d_in[10];
    const float* Wo   = (const float*)d_in[11];
    const float* bo   = (const float*)d_in[12];
    const float* beta = (const float*)d_in[13];

    float* out  = (float*)d_out;                     // [8192,1024]
    float* attn = (float*)d_out + 8388608;           // [16,16,16]

    char* p = (char*)d_ws;
    auto take = [&](size_t n) -> char* {
        char* cur = p; p += (n + 255) & ~(size_t)255; return cur;
    };
    f16_t* Aq = (f16_t*)take(16777216);
    f16_t* Ak = (f16_t*)take(16777216);
    f16_t* Av = (f16_t*)take(16777216);
    f16_t* Bq = (f16_t*)take(2097152);
    f16_t* Bk = (f16_t*)take(2097152);
    f16_t* Bv = (f16_t*)take(2097152);
    f16_t* Bo = (f16_t*)take(2097152);
    f16_t* Pq16 = (f16_t*)take(16777216);
    f16_t* Pk16 = (f16_t*)take(16777216);
    f16_t* Pv16 = (f16_t*)take(16777216);
    float* part = (float*)take(262144);              // 16x16x256 partials
    f16_t* xmix = Aq;  // Aq dead after gemm3; reuse for xmix

    pack_kernel<<<14336, 256, 0, stream>>>(q, k, v, Wq, Wk, Wv, Wo,
                                           Aq, Ak, Av, Bq, Bk, Bv, Bo);

    Gemm3Args ga;
    ga.A[0] = Aq; ga.A[1] = Ak; ga.A[2] = Av;
    ga.B[0] = Bq; ga.B[1] = Bk; ga.B[2] = Bv;
    ga.bias[0] = bq; ga.bias[1] = bk; ga.bias[2] = bv;
    ga.C16[0] = Pq16; ga.C16[1] = Pk16; ga.C16[2] = Pv16;
    gemm3<<<dim3(64, 8, 3), 256, 0, stream>>>(ga);

    scores_kernel<<<dim3(16, 16), 256, 0, stream>>>(Pq16, Pk16, part);
    mix_kernel<<<512, 256, 0, stream>>>(Pv16, part, beta, attn, xmix);
    gemm_o<<<dim3(64, 8), 256, 0, stream>>>(xmix, Bo, bo, out);
}

// Round 8
// 275.684 us; speedup vs baseline: 1.0793x; 1.0339x over previous
//
#include <hip/hip_runtime.h>
#include <cstdint>
#include <cstddef>

// Dual attention (channel attention), B=16 S=512 D=1024 H=16 dk=64.
// Round 12: kill the q/k/v pack round-trip (96MB read + 48MB write + 48MB
// re-read = ~27us) WITHOUT R9's mistake. R9 failed because A-staging became
// a synchronous load->wait->cvt->ds_write chain (exposed HBM latency,
// VALUBusy DOWN). R12 keeps the proven async global_load_lds staging and
// stages A as RAW F32 (8x16B DMA issues/thread vs 4), converting f32->f16
// AFTER the ds_read, in registers, right before the MFMA (RNE casts =
// bit-identical to pack's conversion -> absmax unchanged).
// A-plane swizzle (16 units/row): LDS unit su holds global unit
// gu = su ^ (row&15); reader su = U ^ arow (row&15 == arow since wave/mt
// offsets are multiples of 16); uniform 2 lanes/4-bank-group = conflict-free.
// LDS 48KB (As32 32K + Bs 16K). B path byte-identical to proven body,
// fed by a weights-only pack (~4us).
// Pre-stated fallback: gemm3 >95us or total >=285 -> revert R11, declare.
// Pipeline:
//   1. pack_w: f32 -> fp16 weights (Wq,Wk,Wv,Wo)
//   2. gemm3 (z=3): Pq16,Pk16,Pv16 = f16(x@W^T+b), x = raw f32 q/k/v
//   3. scores: part[(b,slice),i*16+j] = sum_{s in slice,c} Qf Kf  (MFMA)
//   4. mix: per-block softmax(part sum, x0.25) -> Mm = I + beta*attn;
//      xmix[r,64i+c] = f16( sum_j Mm[i,j]*Pv16[r,64j+c] ); attn -> d_out
//   5. out = f16 GEMM(xmix, Wo^T) + bo -> d_out
// mask (d_in[3]) and adj (d_in[4]) are unused by the reference.

#define DIM 1024

typedef _Float16 f16_t;
typedef _Float16 f16x4_t __attribute__((ext_vector_type(4)));
typedef _Float16 f16x8_t __attribute__((ext_vector_type(8)));
typedef float    f32x4_t __attribute__((ext_vector_type(4)));

__device__ __forceinline__ void async_ld16(const void* g, void* l) {
    __builtin_amdgcn_global_load_lds((const __attribute__((address_space(1))) void*)g,
                                     (__attribute__((address_space(3))) void*)l,
                                     16, 0, 0);
}

// ---------------------------------------------------------------- pack_w
// Weights only, 32B/thread (float4 pairs): 4 x 131072 pairs = 524288
// = 2048 blocks exactly.
__global__ __launch_bounds__(256) void pack_w(
    const float* __restrict__ Wq, const float* __restrict__ Wk,
    const float* __restrict__ Wv, const float* __restrict__ Wo,
    f16_t* __restrict__ Bq, f16_t* __restrict__ Bk,
    f16_t* __restrict__ Bv, f16_t* __restrict__ Bo)
{
    const int u = blockIdx.x * 256 + threadIdx.x;
    const float* src; f16_t* dst; int i;
    if (u < 131072)       { src = Wq; dst = Bq; i = u; }
    else if (u < 262144)  { src = Wk; dst = Bk; i = u - 131072; }
    else if (u < 393216)  { src = Wv; dst = Bv; i = u - 262144; }
    else                  { src = Wo; dst = Bo; i = u - 393216; }
    float4 s0 = ((const float4*)src)[2 * i];
    float4 s1 = ((const float4*)src)[2 * i + 1];
    f16x8_t h;
    h[0] = (f16_t)s0.x; h[1] = (f16_t)s0.y; h[2] = (f16_t)s0.z; h[3] = (f16_t)s0.w;
    h[4] = (f16_t)s1.x; h[5] = (f16_t)s1.y; h[6] = (f16_t)s1.z; h[7] = (f16_t)s1.w;
    ((f16x8_t*)dst)[i] = h;
}

// ------------------------------------------- projection GEMM (f32 A, DMA)
// C16[m,n] = f16( sum_k (f16)A[m,k] * B[n,k] + bias[n] ). A [8192,1024] f32
// raw input, B [1024,1024] f16 packed weights. Tile 128x128, BK=64, 4 waves.
// A staged as f32 via global_load_lds (async, 8 issues/thread/K-step);
// f32->f16 RNE conversion in registers after ds_read (bit-identical to the
// old pack path). B staging/read path byte-identical to the proven body.
__device__ __forceinline__ void gemm_body_qkv(
    const float* __restrict__ A, const f16_t* __restrict__ B,
    const float* __restrict__ bias, f16_t* __restrict__ C16,
    float* As32, f16_t* Bs, int tileM, int tileN)
{
    const int tid  = threadIdx.x;
    const int lane = tid & 63;
    const int w    = tid >> 6;
    const int wm = (w & 1) << 6;
    const int wn = (w >> 1) << 6;

    f32x4_t acc[4][4];
#pragma unroll
    for (int i = 0; i < 4; ++i)
#pragma unroll
        for (int j = 0; j < 4; ++j)
            acc[i][j] = (f32x4_t){0.f, 0.f, 0.f, 0.f};

    // B staging constants (proven body)
    const int srow = lane >> 3;
    const int scol = ((lane & 7) ^ (lane >> 3)) << 3;
    // A staging constants: issue s writes units n = s*256 + w*64 + lane;
    // row = n>>4 = s*16 + rlo, su = lane&15, source unit gu = su ^ (row&15).
    const int rlo = (w << 2) + (lane >> 4);             // row&15, s-independent
    const int gu  = (lane & 15) ^ rlo;                  // global 16B-unit
    const float* srcA0 = A + (size_t)(tileM + rlo) * DIM + (gu << 2);
    // fragment-read constants
    const int arow = lane & 15;
    const int kqu  = lane >> 4;
    const int sx   = lane & 7;

    for (int kt = 0; kt < 16; ++kt) {
        const int k0 = kt << 6;                         // elems (f32 A, f16 B)
#pragma unroll
        for (int t4 = 0; t4 < 4; ++t4) {                // B: 16KB f16
            const int row = (w << 5) + (t4 << 3);
            async_ld16(B + (size_t)(tileN + row + srow) * DIM + k0 + scol,
                       (void*)(Bs + row * 64));
        }
#pragma unroll
        for (int s = 0; s < 8; ++s)                     // A: 32KB f32
            async_ld16(srcA0 + (size_t)(s << 4) * DIM + k0,
                       (void*)(As32 + (s << 10) + (w << 8)));
        __syncthreads();
#pragma unroll
        for (int kk = 0; kk < 2; ++kk) {
            const int cu = ((kk << 2) + kqu) ^ sx;      // B swizzled unit
            const int U0 = (kk << 3) + (kqu << 1);      // A units (2 per frag)
            const int S0 = U0 ^ arow;
            const int S1 = (U0 + 1) ^ arow;
            f16x8_t af[4], bfv[4];
#pragma unroll
            for (int mt = 0; mt < 4; ++mt) {
                const float* rb = As32 + (wm + (mt << 4) + arow) * 64;
                f32x4_t lo = *(const f32x4_t*)(rb + (S0 << 2));
                f32x4_t hi = *(const f32x4_t*)(rb + (S1 << 2));
                f16x8_t h;
                h[0] = (f16_t)lo[0]; h[1] = (f16_t)lo[1];
                h[2] = (f16_t)lo[2]; h[3] = (f16_t)lo[3];
                h[4] = (f16_t)hi[0]; h[5] = (f16_t)hi[1];
                h[6] = (f16_t)hi[2]; h[7] = (f16_t)hi[3];
                af[mt] = h;
            }
#pragma unroll
            for (int nt = 0; nt < 4; ++nt)
                bfv[nt] = *(const f16x8_t*)(Bs + (wn + (nt << 4) + arow) * 64 + (cu << 3));
#pragma unroll
            for (int mt = 0; mt < 4; ++mt)
#pragma unroll
                for (int nt = 0; nt < 4; ++nt)
                    acc[mt][nt] = __builtin_amdgcn_mfma_f32_16x16x32_f16(
                        af[mt], bfv[nt], acc[mt][nt], 0, 0, 0);
        }
        __syncthreads();
    }

    // C/D layout: col = lane&15, row = (lane>>4)*4 + reg
    const int rq = (lane >> 4) << 2;
#pragma unroll
    for (int nt = 0; nt < 4; ++nt) {
        const int col = tileN + wn + (nt << 4) + arow;
        const float bv = bias[col];
#pragma unroll
        for (int mt = 0; mt < 4; ++mt) {
            const int row = tileM + wm + (mt << 4) + rq;
#pragma unroll
            for (int r = 0; r < 4; ++r)
                C16[(size_t)(row + r) * DIM + col] = (f16_t)(acc[mt][nt][r] + bv);
        }
    }
}

struct Gemm3Args {
    const float* A[3];    // raw f32 q, k, v
    const f16_t* B[3];    // packed f16 weights
    const float* bias[3];
    f16_t*       C16[3];  // Pq16, Pk16, Pv16
};

// three projection GEMMs in one launch: grid (64, 8, 3) = 1536 blocks
__global__ __launch_bounds__(256) void gemm3(Gemm3Args args)
{
    __shared__ __align__(16) float As32[128 * 64];   // 32KB
    __shared__ __align__(16) f16_t Bs[128 * 64];     // 16KB
    const int z = blockIdx.z;
    gemm_body_qkv(args.A[z], args.B[z], args.bias[z], args.C16[z],
                  As32, Bs, blockIdx.x * 128, blockIdx.y * 128);
}

// ---------------------------------------------------------------- gemm_o
// R0-proven all-f16 body (both operands via global_load_lds), f32 out.
__global__ __launch_bounds__(256) void gemm_o(
    const f16_t* __restrict__ A, const f16_t* __restrict__ B,
    const float* __restrict__ bias, float* __restrict__ C)
{
    __shared__ __align__(16) f16_t As[128 * 64];
    __shared__ __align__(16) f16_t Bs[128 * 64];
    const int tileM = blockIdx.x * 128, tileN = blockIdx.y * 128;
    const int tid  = threadIdx.x;
    const int lane = tid & 63;
    const int w    = tid >> 6;
    const int wm = (w & 1) << 6;
    const int wn = (w >> 1) << 6;

    f32x4_t acc[4][4];
#pragma unroll
    for (int i = 0; i < 4; ++i)
#pragma unroll
        for (int j = 0; j < 4; ++j)
            acc[i][j] = (f32x4_t){0.f, 0.f, 0.f, 0.f};

    const int srow = lane >> 3;
    const int scol = ((lane & 7) ^ (lane >> 3)) << 3;
    const int arow = lane & 15;
    const int sx   = lane & 7;
    const int kqu  = lane >> 4;

    for (int kt = 0; kt < 16; ++kt) {
        const int k0 = kt << 6;
#pragma unroll
        for (int t4 = 0; t4 < 4; ++t4) {
            const int row = (w << 5) + (t4 << 3);
            async_ld16(A + (size_t)(tileM + row + srow) * DIM + k0 + scol,
                       (void*)(As + row * 64));
            async_ld16(B + (size_t)(tileN + row + srow) * DIM + k0 + scol,
                       (void*)(Bs + row * 64));
        }
        __syncthreads();
#pragma unroll
        for (int kk = 0; kk < 2; ++kk) {
            const int cu = ((kk << 2) + kqu) ^ sx;
            f16x8_t af[4], bfv[4];
#pragma unroll
            for (int mt = 0; mt < 4; ++mt)
                af[mt] = *(const f16x8_t*)(As + (wm + (mt << 4) + arow) * 64 + (cu << 3));
#pragma unroll
            for (int nt = 0; nt < 4; ++nt)
                bfv[nt] = *(const f16x8_t*)(Bs + (wn + (nt << 4) + arow) * 64 + (cu << 3));
#pragma unroll
            for (int mt = 0; mt < 4; ++mt)
#pragma unroll
                for (int nt = 0; nt < 4; ++nt)
                    acc[mt][nt] = __builtin_amdgcn_mfma_f32_16x16x32_f16(
                        af[mt], bfv[nt], acc[mt][nt], 0, 0, 0);
        }
        __syncthreads();
    }

    const int rq = (lane >> 4) << 2;
#pragma unroll
    for (int nt = 0; nt < 4; ++nt) {
        const int col = tileN + wn + (nt << 4) + arow;
        const float bv = bias[col];
#pragma unroll
        for (int mt = 0; mt < 4; ++mt) {
            const int row = tileM + wm + (mt << 4) + rq;
#pragma unroll
            for (int r = 0; r < 4; ++r)
                C[(size_t)(row + r) * DIM + col] = acc[mt][nt][r] + bv;
        }
    }
}

// ---------------------------------------------------------------- scores
// part[(b*16+slice)*256 + i*16+j] = sum_{s in slice, c} Qf[b,i,s*64+c] *
// Kf[b,j,s*64+c]. Grid (16 b, 16 slices) = 256 blocks; wave w owns rows
// s = slice*32 + w*8 .. +7. No atomics, no fences (R7/R8 lesson).
__global__ __launch_bounds__(256) void scores_kernel(
    const f16_t* __restrict__ Pq16, const f16_t* __restrict__ Pk16,
    float* __restrict__ part)
{
    __shared__ float red[4][256];
    const int b = blockIdx.x;
    const int slice = blockIdx.y;
    const int lane = threadIdx.x & 63;
    const int w = threadIdx.x >> 6;
    const int m  = lane & 15;              // i (A rows) / j (B rows)
    const int q8 = (lane >> 4) << 3;       // k-offset within 32-chunk

    f32x4_t acc = (f32x4_t){0.f, 0.f, 0.f, 0.f};
    const int s0 = slice * 32 + w * 8;
#pragma unroll
    for (int ss = 0; ss < 8; ++ss) {
        const size_t rb = (size_t)(b * 512 + s0 + ss) * DIM;
        const f16_t* qrow = Pq16 + rb;
        const f16_t* krow = Pk16 + rb;
#pragma unroll
        for (int c0 = 0; c0 < 64; c0 += 32) {
            f16x8_t af = *(const f16x8_t*)(qrow + m * 64 + c0 + q8);
            f16x8_t bf = *(const f16x8_t*)(krow + m * 64 + c0 + q8);
            acc = __builtin_amdgcn_mfma_f32_16x16x32_f16(af, bf, acc, 0, 0, 0);
        }
    }
    // C/D: col(j) = lane&15, row(i) = (lane>>4)*4 + r
    const int rq = (lane >> 4) << 2;
#pragma unroll
    for (int r = 0; r < 4; ++r)
        red[w][(rq + r) * 16 + m] = acc[r];
    __syncthreads();
    const int t = threadIdx.x;
    part[(size_t)(b * 16 + slice) * 256 + t] =
        red[0][t] + red[1][t] + red[2][t] + red[3][t];
}

// ------------------------------------------------- channel mix (+softmax)
// Each block computes its batch's softmax from part redundantly (L2-hot,
// threads 0..15: thread i owns row i), builds Mm = I + beta*attn in LDS,
// then mixes with vectorized 16B/lane V loads: thread t = (rloc=t>>4,
// i8=(t>>3)&1, u=t&7); r = blk*16+rloc; v[j] = Pv16[r, j*64+u*8..+7];
// xmix[r, i*64+u*8+c] = f16( sum_j Msh[i*16+j]*v[j][c] ), i in i8*8..+7.
// Grid 512 blocks x 16 rows. One block per batch (blockIdx.x%32==0)
// writes attn to d_out.
__global__ __launch_bounds__(256) void mix_kernel(
    const f16_t* __restrict__ Pv16, const float* __restrict__ part,
    const float* __restrict__ beta_p,
    float* __restrict__ attn_out, f16_t* __restrict__ xmix)
{
    __shared__ float Msh[256];
    const int rbase = blockIdx.x * 16;
    const int b = blockIdx.x >> 5;         // 32 blocks per batch
    const int t = threadIdx.x;
    if (t < 16) {
        const int i = t;
        float s[16];
#pragma unroll
        for (int j = 0; j < 16; ++j) s[j] = 0.f;
#pragma unroll 4
        for (int sl = 0; sl < 16; ++sl) {
            const float* pp = part + (size_t)(b * 16 + sl) * 256 + i * 16;
#pragma unroll
            for (int j4 = 0; j4 < 4; ++j4) {
                float4 v4 = ((const float4*)pp)[j4];
                s[j4 * 4 + 0] += v4.x; s[j4 * 4 + 1] += v4.y;
                s[j4 * 4 + 2] += v4.z; s[j4 * 4 + 3] += v4.w;
            }
        }
        float mx = -1e30f;
#pragma unroll
        for (int j = 0; j < 16; ++j) {
            s[j] *= 0.25f;                 // 1/sqrt(h), h=16
            mx = fmaxf(mx, s[j]);
        }
        float sum = 0.f;
#pragma unroll
        for (int j = 0; j < 16; ++j) { s[j] = expf(s[j] - mx); sum += s[j]; }
        const float inv = 1.f / sum;
        const float beta = beta_p[0];
        const bool wr_attn = (blockIdx.x & 31) == 0;
#pragma unroll
        for (int j = 0; j < 16; ++j) {
            float a = s[j] * inv;
            if (wr_attn) attn_out[(b * 16 + i) * 16 + j] = a;
            Msh[i * 16 + j] = beta * a + ((j == i) ? 1.f : 0.f);
        }
    }
    __syncthreads();
    const int u    = t & 7;                // 8-channel unit within head
    const int i8   = (t >> 3) & 1;         // i half (0: i=0..7, 1: i=8..15)
    const int rloc = t >> 4;               // row within block (0..15)
    const int r = rbase + rloc;
    const f16_t* vrow = Pv16 + (size_t)r * DIM + u * 8;
    f16x8_t v[16];
#pragma unroll
    for (int j = 0; j < 16; ++j)
        v[j] = *(const f16x8_t*)(vrow + j * 64);
    f16_t* orow = xmix + (size_t)r * DIM + u * 8;
#pragma unroll
    for (int ii = 0; ii < 8; ++ii) {
        const int i = i8 * 8 + ii;
        const float* mrow = Msh + i * 16;
        float acc[8];
#pragma unroll
        for (int c = 0; c < 8; ++c) acc[c] = 0.f;
#pragma unroll
        for (int j = 0; j < 16; ++j) {
            const float m = mrow[j];
#pragma unroll
            for (int c = 0; c < 8; ++c)
                acc[c] += m * (float)v[j][c];   // v_fma_mix
        }
        f16x8_t o;
#pragma unroll
        for (int c = 0; c < 8; ++c) o[c] = (f16_t)acc[c];
        *(f16x8_t*)(orow + i * 64) = o;
    }
}

// ---------------------------------------------------------------- launch
extern "C" void kernel_launch(void* const* d_in, const int* in_sizes, int n_in,
                              void* d_out, int out_size, void* d_ws, size_t ws_size,
                              hipStream_t stream)
{
    (void)in_sizes; (void)n_in; (void)out_size; (void)ws_size;
    const float* q    = (const float*)d_in[0];
    const float* k    = (const float*)d_in[1];
    const float* v    = (const float*)d_in[2];
    // d_in[3] mask, d_in[4] adj: unused by reference
    const float* Wq   = (const float*)d_in[5];
    const float* bq   = (const float*)d_in[6];
    const float* Wk   = (const float*)d_in[7];
    const float* bk   = (const float*)d_in[8];
    const float* Wv   = (const float*)d_in[9];
    const float* bv   = (const float*)d_in[10];
    const float* Wo   = (const float*)d_in[11];
    const float* bo   = (const float*)d_in[12];
    const float* beta = (const float*)d_in[13];

    float* out  = (float*)d_out;                     // [8192,1024]
    float* attn = (float*)d_out + 8388608;           // [16,16,16]

    char* p = (char*)d_ws;
    auto take = [&](size_t n) -> char* {
        char* cur = p; p += (n + 255) & ~(size_t)255; return cur;
    };
    f16_t* Bq = (f16_t*)take(2097152);
    f16_t* Bk = (f16_t*)take(2097152);
    f16_t* Bv = (f16_t*)take(2097152);
    f16_t* Bo = (f16_t*)take(2097152);
    f16_t* Pq16 = (f16_t*)take(16777216);
    f16_t* Pk16 = (f16_t*)take(16777216);
    f16_t* Pv16 = (f16_t*)take(16777216);
    f16_t* xmix = (f16_t*)take(16777216);
    float* part = (float*)take(262144);              // 16x16x256 partials

    pack_w<<<2048, 256, 0, stream>>>(Wq, Wk, Wv, Wo, Bq, Bk, Bv, Bo);

    Gemm3Args ga;
    ga.A[0] = q; ga.A[1] = k; ga.A[2] = v;
    ga.B[0] = Bq; ga.B[1] = Bk; ga.B[2] = Bv;
    ga.bias[0] = bq; ga.bias[1] = bk; ga.bias[2] = bv;
    ga.C16[0] = Pq16; ga.C16[1] = Pk16; ga.C16[2] = Pv16;
    gemm3<<<dim3(64, 8, 3), 256, 0, stream>>>(ga);

    scores_kernel<<<dim3(16, 16), 256, 0, stream>>>(Pq16, Pk16, part);
    mix_kernel<<<512, 256, 0, stream>>>(Pv16, part, beta, attn, xmix);
    gemm_o<<<dim3(64, 8), 256, 0, stream>>>(xmix, Bo, bo, out);
}